// Round 4
// baseline (3943.488 us; speedup 1.0000x reference)
//
#include <hip/hip_runtime.h>

// ---- model constants (match reference) ----
#define VOCAB   4096
#define ETYPES  500
#define DIM     128     // EMBED == HIDDEN == 128
#define OUTC    25
#define MV      20
#define NLAYERS 2
#define NGRAPH  64
#define DECAYF  0.01f
#define KC      512     // k-chunk for attn kernel LDS staging
#define SCAN_B  512     // elements per scan block

// ---------------------------------------------------------------------------
// dst[r][h] = dot(src[r], lin_w[h]) + lin_b[h]   (rows of width DIM)
__global__ void k_rowlin(const float* __restrict__ src, float* __restrict__ dst,
                         const float* __restrict__ lin_w, const float* __restrict__ lin_b) {
    int r = blockIdx.x, h = threadIdx.x;
    __shared__ float s[DIM];
    s[h] = src[(size_t)r * DIM + h];
    __syncthreads();
    const float4* w4 = (const float4*)(lin_w + (size_t)h * DIM);
    const float4* s4 = (const float4*)s;
    float acc = lin_b[h];
#pragma unroll
    for (int k = 0; k < DIM / 4; k++) {
        float4 a = s4[k]; float4 b = w4[k];
        acc += a.x * b.x + a.y * b.y + a.z * b.z + a.w * b.w;
    }
    dst[(size_t)r * DIM + h] = acc;
}

// ---------------------------------------------------------------------------
// evec[l][t][h] = (dot(elk[t], wr_w[l]) + wr_b[l]) * elk[t][h]
__global__ void k_evec(const float* __restrict__ elk, const float* __restrict__ wr_w,
                       const float* __restrict__ wr_b, float* __restrict__ evec) {
    int idx = blockIdx.x;
    int l = idx / ETYPES, t = idx % ETYPES;
    int h = threadIdx.x;
    float eh = elk[(size_t)t * DIM + h];
    float p = eh * wr_w[l * DIM + h];
    for (int off = 32; off; off >>= 1) p += __shfl_down(p, off, 64);
    __shared__ float ws2[2];
    if ((threadIdx.x & 63) == 0) ws2[threadIdx.x >> 6] = p;
    __syncthreads();
    float wr = ws2[0] + ws2[1] + wr_b[l];
    evec[((size_t)l * ETYPES + t) * DIM + h] = wr * eh;
}

// ---------------------------------------------------------------------------
// beta[l][b][j] = tanh(dot(visit_node[b,j], beta_w[l]) + beta_b[l]) * exp(DECAY*(MV-j))
__global__ void k_beta(const float* __restrict__ visit_node, const float* __restrict__ beta_w,
                       const float* __restrict__ beta_b, float* __restrict__ beta) {
    int idx = blockIdx.x;
    int l = idx >> 6, b = idx & 63;
    int wave = threadIdx.x >> 6, lane = threadIdx.x & 63;
    const float* bw = beta_w + (size_t)l * VOCAB;
    for (int j = wave; j < MV; j += 4) {
        const float* vn = visit_node + ((size_t)b * MV + j) * VOCAB;
        float acc = 0.f;
        for (int k = lane * 4; k < VOCAB; k += 256) {
            float4 a = *(const float4*)(vn + k);
            float4 w = *(const float4*)(bw + k);
            acc += a.x * w.x + a.y * w.y + a.z * w.z + a.w * w.w;
        }
        for (int off = 32; off; off >>= 1) acc += __shfl_down(acc, off, 64);
        if (lane == 0) {
            float lam = __expf(DECAYF * (float)(MV - j));
            beta[((size_t)l * NGRAPH + b) * MV + j] = tanhf(acc + beta_b[l]) * lam;
        }
    }
}

// ---------------------------------------------------------------------------
// gstart[b] = first index i with batch[i] >= b  (batch is sorted); gstart[NGRAPH] = N
__global__ void k_gbounds(const int* __restrict__ batch, int n_nodes, int* __restrict__ gstart) {
    int b = threadIdx.x;
    if (b > NGRAPH) return;
    int lo = 0, hi = n_nodes;
    while (lo < hi) { int mid = (lo + hi) >> 1; if (batch[mid] < b) lo = mid + 1; else hi = mid; }
    gstart[b] = lo;
}

// ---------------------------------------------------------------------------
// ---- CSR-by-dst build: histogram -> scan -> scatter (per-call, capture-safe)
__global__ void k_hist(const int* __restrict__ edst, int* __restrict__ cnt, int n_edges) {
    int e = blockIdx.x * 256 + threadIdx.x;
    if (e < n_edges) atomicAdd(&cnt[edst[e]], 1);
}

// per-block reduce of SCAN_B counts -> bsum[block]
__global__ void k_scan1(const int* __restrict__ cnt, int* __restrict__ bsum, int n_nodes) {
    __shared__ int s[256];
    int base = blockIdx.x * SCAN_B;
    int v = 0;
    int i0 = base + threadIdx.x;
    if (i0 < n_nodes) v += cnt[i0];
    if (i0 + 256 < n_nodes) v += cnt[i0 + 256];
    s[threadIdx.x] = v;
    __syncthreads();
    for (int st = 128; st > 0; st >>= 1) {
        if (threadIdx.x < st) s[threadIdx.x] += s[threadIdx.x + st];
        __syncthreads();
    }
    if (threadIdx.x == 0) bsum[blockIdx.x] = s[0];
}

// single-block inclusive scan of bsum (nb <= 256)
__global__ void k_scan2(int* __restrict__ bsum, int nb) {
    __shared__ int s[256];
    int t = threadIdx.x;
    s[t] = (t < nb) ? bsum[t] : 0;
    __syncthreads();
    for (int st = 1; st < 256; st <<= 1) {
        int u = (t >= st) ? s[t - st] : 0;
        __syncthreads();
        s[t] += u;
        __syncthreads();
    }
    if (t < nb) bsum[t] = s[t];   // inclusive
}

// per-block exclusive scan + base -> offsets, cursor; offsets[N] gets E
__global__ void k_scan3(const int* __restrict__ cnt, const int* __restrict__ bsum,
                        int* __restrict__ offsets, int* __restrict__ cursor, int n_nodes) {
    __shared__ int s[SCAN_B];
    int b = blockIdx.x;
    int base = b * SCAN_B;
    int t = threadIdx.x;                       // 512 threads
    int v = (base + t < n_nodes) ? cnt[base + t] : 0;
    s[t] = v;
    __syncthreads();
    for (int st = 1; st < SCAN_B; st <<= 1) {
        int u = (t >= st) ? s[t - st] : 0;
        __syncthreads();
        s[t] += u;
        __syncthreads();
    }
    int gbase = (b == 0) ? 0 : bsum[b - 1];
    int excl = gbase + s[t] - v;
    if (base + t <= n_nodes) {
        offsets[base + t] = excl;              // offsets[N] == E falls out naturally
        if (base + t < n_nodes) cursor[base + t] = excl;
    }
}

// Scatter per-edge records:
//   sorted_p[p] = src | (edge_type << 17)   (N = 50000 < 2^17, ETYPES = 500 < 2^15)
//   sorted_v[p] = node_ids[src]             (vocab id; lives in the x0 overlay,
//                                            consumed only by layer-0 aggconv)
__global__ void k_scatter(const int* __restrict__ edst, const int* __restrict__ esrc,
                          const int* __restrict__ edge_ids, const int* __restrict__ node_ids,
                          int* __restrict__ cursor, unsigned* __restrict__ sorted_p,
                          unsigned* __restrict__ sorted_v, int n_edges) {
    int e = blockIdx.x * 256 + threadIdx.x;
    if (e < n_edges) {
        int s = esrc[e];
        int p = atomicAdd(&cursor[edst[e]], 1);
        sorted_p[p] = (unsigned)s | ((unsigned)edge_ids[e] << 17);
        sorted_v[p] = (unsigned)node_ids[s];
    }
}

// ---------------------------------------------------------------------------
// Per-node attention: attnn[i] = sum_j softmax_j(visit_node[b]·alpha_w[v]) * beta[b][j]
__global__ __launch_bounds__(256, 2) void k_attn_node(
        const float* __restrict__ visit_node, const float* __restrict__ alpha_w_l,
        const float* __restrict__ beta_l, const int* __restrict__ node_ids,
        const int* __restrict__ gstart, float* __restrict__ attnn) {
    __shared__ float As[MV][KC + 4];
    int b = blockIdx.x;
    int start = gstart[b], end = gstart[b + 1];
    int wave = threadIdx.x >> 6, lane = threadIdx.x & 63;
    const float* bet = beta_l + (size_t)b * MV;

    for (int base = start + blockIdx.y * 16; base < end; base += gridDim.y * 16) {
        int n0 = base + wave * 4;
        int v[4]; bool valid[4];
#pragma unroll
        for (int i = 0; i < 4; i++) {
            int n = n0 + i;
            valid[i] = (n < end);
            v[i] = valid[i] ? node_ids[n] : 0;
        }
        float acc[4][MV];
#pragma unroll
        for (int i = 0; i < 4; i++)
#pragma unroll
            for (int j = 0; j < MV; j++) acc[i][j] = 0.f;

        for (int k0 = 0; k0 < VOCAB; k0 += KC) {
            __syncthreads();
            for (int idx = threadIdx.x; idx < MV * (KC / 4); idx += 256) {
                int j = idx / (KC / 4), kq = idx % (KC / 4);
                float4 vv = *(const float4*)(visit_node + ((size_t)b * MV + j) * VOCAB + k0 + kq * 4);
                *(float4*)&As[j][kq * 4] = vv;
            }
            __syncthreads();
#pragma unroll
            for (int step = 0; step < KC / 256; step++) {
                int kk = step * 256 + lane * 4;
                float4 a[4];
#pragma unroll
                for (int i = 0; i < 4; i++)
                    a[i] = *(const float4*)(alpha_w_l + (size_t)v[i] * VOCAB + k0 + kk);
#pragma unroll
                for (int j = 0; j < MV; j++) {
                    float4 s = *(const float4*)&As[j][kk];
#pragma unroll
                    for (int i = 0; i < 4; i++)
                        acc[i][j] += a[i].x * s.x + a[i].y * s.y + a[i].z * s.z + a[i].w * s.w;
                }
            }
        }
#pragma unroll
        for (int i = 0; i < 4; i++)
#pragma unroll
            for (int j = 0; j < MV; j++)
                for (int off = 32; off; off >>= 1)
                    acc[i][j] += __shfl_xor(acc[i][j], off, 64);

#pragma unroll
        for (int i = 0; i < 4; i++) {
            if (!valid[i]) continue;
            float m = -1e30f;
#pragma unroll
            for (int j = 0; j < MV; j++) m = fmaxf(m, acc[i][j]);
            float den = 0.f, num = 0.f;
#pragma unroll
            for (int j = 0; j < MV; j++) {
                float e = __expf(acc[i][j] - m);
                den += e;
                num += e * bet[j];
            }
            if (lane == 0) attnn[n0 + i] = num / den;
        }
    }
}

// ---------------------------------------------------------------------------
// Fused aggregate + GIN conv, CSR by dst (no atomics).
// Block = 256 thr = 4 waves; wave w aggregates node n0+w, lane handles dims
// 2*lane, 2*lane+1 (float2).  Edge loop unrolled by 4 with NAMED SCALARS only
// (no arrays -> guaranteed registers, no scratch spill).
// USE_TAB=1 (layer 0): x rows come from the 4096-row x0lk table (2 MB, L2-
// resident) indexed by the sorted_v vocab stream -- bit-identical to
// gathering the staged x0[src] row.
template<int USE_TAB>
__global__ __launch_bounds__(256, 4) void k_aggconv(
        const float* __restrict__ xin, const float* __restrict__ xtab,
        const int* __restrict__ node_ids, float* __restrict__ xout,
        const float* __restrict__ attnn, const float* __restrict__ evec_l,
        const unsigned* __restrict__ sorted_p, const unsigned* __restrict__ sorted_v,
        const int* __restrict__ offsets,
        const float* __restrict__ conv_w_l, const float* __restrict__ conv_b_l,
        const float* __restrict__ eps, int l, int n_nodes) {
    int n0 = blockIdx.x * 4;
    int wave = threadIdx.x >> 6, lane = threadIdx.x & 63;
    int lane2 = lane * 2;
    int n = n0 + wave;
    __shared__ float t[4][DIM];
    float c = 1.0f + eps[l];

    if (n < n_nodes) {
        float accx = 0.f, accy = 0.f;
        int i0 = offsets[n], i1 = offsets[n + 1];
        int idx = i0;
        for (; idx + 4 <= i1; idx += 4) {
            unsigned p0 = sorted_p[idx];
            unsigned p1 = sorted_p[idx + 1];
            unsigned p2 = sorted_p[idx + 2];
            unsigned p3 = sorted_p[idx + 3];
            unsigned r0 = USE_TAB ? sorted_v[idx]     : (p0 & 0x1FFFFu);
            unsigned r1 = USE_TAB ? sorted_v[idx + 1] : (p1 & 0x1FFFFu);
            unsigned r2 = USE_TAB ? sorted_v[idx + 2] : (p2 & 0x1FFFFu);
            unsigned r3 = USE_TAB ? sorted_v[idx + 3] : (p3 & 0x1FFFFu);
            const float* xb = USE_TAB ? xtab : xin;
            float a0 = attnn[p0 & 0x1FFFFu];
            float a1 = attnn[p1 & 0x1FFFFu];
            float a2 = attnn[p2 & 0x1FFFFu];
            float a3 = attnn[p3 & 0x1FFFFu];
            float2 xv0 = *(const float2*)(xb + (size_t)r0 * DIM + lane2);
            float2 xv1 = *(const float2*)(xb + (size_t)r1 * DIM + lane2);
            float2 xv2 = *(const float2*)(xb + (size_t)r2 * DIM + lane2);
            float2 xv3 = *(const float2*)(xb + (size_t)r3 * DIM + lane2);
            float2 ev0 = *(const float2*)(evec_l + (size_t)(p0 >> 17) * DIM + lane2);
            float2 ev1 = *(const float2*)(evec_l + (size_t)(p1 >> 17) * DIM + lane2);
            float2 ev2 = *(const float2*)(evec_l + (size_t)(p2 >> 17) * DIM + lane2);
            float2 ev3 = *(const float2*)(evec_l + (size_t)(p3 >> 17) * DIM + lane2);
            accx += fmaxf(xv0.x * a0 + ev0.x, 0.f);
            accy += fmaxf(xv0.y * a0 + ev0.y, 0.f);
            accx += fmaxf(xv1.x * a1 + ev1.x, 0.f);
            accy += fmaxf(xv1.y * a1 + ev1.y, 0.f);
            accx += fmaxf(xv2.x * a2 + ev2.x, 0.f);
            accy += fmaxf(xv2.y * a2 + ev2.y, 0.f);
            accx += fmaxf(xv3.x * a3 + ev3.x, 0.f);
            accy += fmaxf(xv3.y * a3 + ev3.y, 0.f);
        }
        for (; idx < i1; idx++) {
            unsigned p = sorted_p[idx];
            unsigned r = USE_TAB ? sorted_v[idx] : (p & 0x1FFFFu);
            const float* xb = USE_TAB ? xtab : xin;
            float av = attnn[p & 0x1FFFFu];
            float2 xv = *(const float2*)(xb + (size_t)r * DIM + lane2);
            float2 ev = *(const float2*)(evec_l + (size_t)(p >> 17) * DIM + lane2);
            accx += fmaxf(xv.x * av + ev.x, 0.f);
            accy += fmaxf(xv.y * av + ev.y, 0.f);
        }
        const float* selfr = USE_TAB ? xtab + (size_t)node_ids[n] * DIM : xin + (size_t)n * DIM;
        float2 xn = *(const float2*)(selfr + lane2);
        t[wave][lane2]     = accx + c * xn.x;
        t[wave][lane2 + 1] = accy + c * xn.y;
    }
    __syncthreads();

    int h = threadIdx.x & 127;
    int g = threadIdx.x >> 7;                  // handles nodes g and g+2
    const float4* w4 = (const float4*)(conv_w_l + (size_t)h * DIM);
    float cb = conv_b_l[h];
    float acc0 = cb, acc1 = cb;
#pragma unroll
    for (int k = 0; k < DIM / 4; k++) {
        float4 w = w4[k];
        float4 u0 = *(const float4*)&t[g][k * 4];
        float4 u1 = *(const float4*)&t[g + 2][k * 4];
        acc0 += w.x * u0.x + w.y * u0.y + w.z * u0.z + w.w * u0.w;
        acc1 += w.x * u1.x + w.y * u1.y + w.z * u1.z + w.w * u1.w;
    }
    if (n0 + g < n_nodes)     xout[(size_t)(n0 + g) * DIM + h]     = fmaxf(acc0, 0.f);
    if (n0 + g + 2 < n_nodes) xout[(size_t)(n0 + g + 2) * DIM + h] = fmaxf(acc1, 0.f);
}

// ---------------------------------------------------------------------------
// gsum[b][h] = mean over nodes of graph b of x[i][h]
__global__ void k_pool(const float* __restrict__ x, const int* __restrict__ gstart,
                       float* __restrict__ gsum) {
    int b = blockIdx.x;
    int start = gstart[b], end = gstart[b + 1];
    int half = threadIdx.x >> 7, h = threadIdx.x & 127;
    float acc = 0.f;
    for (int i = start + half; i < end; i += 2) acc += x[(size_t)i * DIM + h];
    __shared__ float sm[2][DIM];
    sm[half][h] = acc;
    __syncthreads();
    if (half == 0) {
        int cnt = end - start;
        gsum[(size_t)b * DIM + h] = (sm[0][h] + sm[1][h]) / (float)(cnt > 1 ? cnt : 1);
    }
}

// ---------------------------------------------------------------------------
// xnode[b][d] = (sum_v ehr[b][v]*node_emb[v][d]) / sum_v ehr[b][v]
__global__ void k_xnode(const float* __restrict__ ehr, const float* __restrict__ node_emb,
                        float* __restrict__ xnode) {
    int b = blockIdx.x, d = threadIdx.x;
    const float* e = ehr + (size_t)b * VOCAB;
    float acc = 0.f;
    for (int v = 0; v < VOCAB; v++) acc += e[v] * node_emb[(size_t)v * DIM + d];
    float ps = 0.f;
    for (int v = d; v < VOCAB; v += DIM) ps += e[v];
    __shared__ float red[DIM];
    red[d] = ps;
    __syncthreads();
    for (int s = DIM / 2; s > 0; s >>= 1) {
        if (d < s) red[d] += red[d + s];
        __syncthreads();
    }
    xnode[(size_t)b * DIM + d] = acc / red[0];
}

// ---------------------------------------------------------------------------
__global__ void k_head(const float* __restrict__ gsum, const float* __restrict__ xnode2,
                       const float* __restrict__ mlp_w, const float* __restrict__ mlp_b,
                       float* __restrict__ out) {
    int b = blockIdx.x, o = threadIdx.x;
    if (o >= OUTC) return;
    const float* w = mlp_w + (size_t)o * 2 * DIM;
    float acc = mlp_b[o];
    for (int h = 0; h < DIM; h++)
        acc += gsum[(size_t)b * DIM + h] * w[h] + xnode2[(size_t)b * DIM + h] * w[DIM + h];
    out[(size_t)b * OUTC + o] = acc;
}

// ---------------------------------------------------------------------------
extern "C" void kernel_launch(void* const* d_in, const int* in_sizes, int n_in,
                              void* d_out, int out_size, void* d_ws, size_t ws_size,
                              hipStream_t stream) {
    const int*   node_ids   = (const int*)d_in[0];
    const int*   edge_ids   = (const int*)d_in[1];
    const int*   edge_index = (const int*)d_in[2];
    const float* visit_node = (const float*)d_in[6];
    const float* ehr        = (const float*)d_in[7];
    const int*   batch      = (const int*)d_in[8];
    const float* node_emb   = (const float*)d_in[10];
    const float* edge_emb   = (const float*)d_in[11];
    const float* lin_w      = (const float*)d_in[12];
    const float* lin_b      = (const float*)d_in[13];
    const float* alpha_w    = (const float*)d_in[14];
    // d_in[15] alpha_b: cancels in softmax over visits — unused
    const float* beta_w     = (const float*)d_in[16];
    const float* beta_b     = (const float*)d_in[17];
    const float* conv_w     = (const float*)d_in[18];
    const float* conv_b     = (const float*)d_in[19];
    const float* wr_w       = (const float*)d_in[20];
    const float* wr_b       = (const float*)d_in[21];
    const float* eps        = (const float*)d_in[22];
    const float* mlp_w      = (const float*)d_in[23];
    const float* mlp_b      = (const float*)d_in[24];
    float* out = (float*)d_out;

    const int N = in_sizes[0];
    const int E = in_sizes[1];
    const int NB = (N + SCAN_B - 1) / SCAN_B;       // scan blocks (<=256)

    // ---- workspace layout (floats) — BYTE-IDENTICAL to the proven round-1
    // layout (58.2 MB). sorted_v is an overlay inside x0: x0 is only written
    // by the layer-1 aggconv, strictly after sorted_v's last read (layer-0
    // aggconv) on the same stream.
    float* w = (float*)d_ws;
    size_t off = 0;
    float* x0     = w + off; off += (size_t)N * DIM;
    float* x1     = w + off; off += (size_t)N * DIM;
    float* attnn  = w + off; off += ((size_t)N + 3) & ~(size_t)3;
    float* beta   = w + off; off += (size_t)NLAYERS * NGRAPH * MV;
    float* x0lk   = w + off; off += (size_t)VOCAB * DIM;
    float* elk    = w + off; off += (size_t)ETYPES * DIM;
    float* evec   = w + off; off += (size_t)NLAYERS * ETYPES * DIM;
    float* gsum   = w + off; off += (size_t)NGRAPH * DIM;
    float* xnode  = w + off; off += (size_t)NGRAPH * DIM;
    float* xnode2 = w + off; off += (size_t)NGRAPH * DIM;
    int*   gstart = (int*)(w + off); off += NGRAPH + 8;
    int*   cnt      = (int*)(w + off); off += (size_t)N + 8;
    int*   offsets  = (int*)(w + off); off += (size_t)N + 8;
    int*   cursor   = (int*)(w + off); off += (size_t)N + 8;
    int*   bsum     = (int*)(w + off); off += 256 + 8;
    unsigned* sorted_p = (unsigned*)(w + off); off += (size_t)E;
    unsigned* sorted_v = (unsigned*)x0;             // overlay (E <= N*DIM)

    const int* esrc = edge_index;
    const int* edst = edge_index + E;

    // ---- CSR-by-dst build ----
    hipMemsetAsync(cnt, 0, (size_t)N * sizeof(int), stream);
    k_hist<<<(E + 255) / 256, 256, 0, stream>>>(edst, cnt, E);
    k_scan1<<<NB, 256, 0, stream>>>(cnt, bsum, N);
    k_scan2<<<1, 256, 0, stream>>>(bsum, NB);
    k_scan3<<<NB, SCAN_B, 0, stream>>>(cnt, bsum, offsets, cursor, N);
    k_scatter<<<(E + 255) / 256, 256, 0, stream>>>(edst, esrc, edge_ids, node_ids,
                                                   cursor, sorted_p, sorted_v, E);

    // ---- precompute tables ----
    k_rowlin<<<VOCAB, DIM, 0, stream>>>(node_emb, x0lk, lin_w, lin_b);
    k_rowlin<<<ETYPES, DIM, 0, stream>>>(edge_emb, elk, lin_w, lin_b);
    k_evec<<<NLAYERS * ETYPES, DIM, 0, stream>>>(elk, wr_w, wr_b, evec);
    k_beta<<<NLAYERS * NGRAPH, 256, 0, stream>>>(visit_node, beta_w, beta_b, beta);
    k_gbounds<<<1, 128, 0, stream>>>(batch, N, gstart);

    // ---- layer 0: x rows come straight from the x0lk vocab table ----
    k_attn_node<<<dim3(NGRAPH, 40), 256, 0, stream>>>(
        visit_node, alpha_w, beta, node_ids, gstart, attnn);
    k_aggconv<1><<<(N + 3) / 4, 256, 0, stream>>>(
        x0lk, x0lk, node_ids, x1, attnn, evec,
        sorted_p, sorted_v, offsets, conv_w, conv_b, eps, 0, N);

    // ---- layer 1: x rows gathered from x1 ----
    k_attn_node<<<dim3(NGRAPH, 40), 256, 0, stream>>>(
        visit_node, alpha_w + (size_t)VOCAB * VOCAB,
        beta + (size_t)NGRAPH * MV, node_ids, gstart, attnn);
    k_aggconv<0><<<(N + 3) / 4, 256, 0, stream>>>(
        x1, x0lk, node_ids, x0, attnn, evec + (size_t)ETYPES * DIM,
        sorted_p, sorted_v, offsets, conv_w + (size_t)DIM * DIM, conv_b + DIM, eps, 1, N);

    // ---- heads ----
    k_pool<<<NGRAPH, 256, 0, stream>>>(x0, gstart, gsum);
    k_xnode<<<NGRAPH, DIM, 0, stream>>>(ehr, node_emb, xnode);
    k_rowlin<<<NGRAPH, DIM, 0, stream>>>(xnode, xnode2, lin_w, lin_b);
    k_head<<<NGRAPH, 64, 0, stream>>>(gsum, xnode2, mlp_w, mlp_b, out);
}

// Round 5
// 2912.801 us; speedup vs baseline: 1.3538x; 1.3538x over previous
//
#include <hip/hip_runtime.h>

// ---- model constants (match reference) ----
#define VOCAB   4096
#define ETYPES  500
#define DIM     128     // EMBED == HIDDEN == 128
#define OUTC    25
#define MV      20
#define NLAYERS 2
#define NGRAPH  64
#define DECAYF  0.01f
#define KC      512     // k-chunk for attn kernel LDS staging
#define SCAN_B  512     // elements per scan block

// ---------------------------------------------------------------------------
// dst[r][h] = dot(src[r], lin_w[h]) + lin_b[h]   (rows of width DIM)
__global__ void k_rowlin(const float* __restrict__ src, float* __restrict__ dst,
                         const float* __restrict__ lin_w, const float* __restrict__ lin_b) {
    int r = blockIdx.x, h = threadIdx.x;
    __shared__ float s[DIM];
    s[h] = src[(size_t)r * DIM + h];
    __syncthreads();
    const float4* w4 = (const float4*)(lin_w + (size_t)h * DIM);
    const float4* s4 = (const float4*)s;
    float acc = lin_b[h];
#pragma unroll
    for (int k = 0; k < DIM / 4; k++) {
        float4 a = s4[k]; float4 b = w4[k];
        acc += a.x * b.x + a.y * b.y + a.z * b.z + a.w * b.w;
    }
    dst[(size_t)r * DIM + h] = acc;
}

// ---------------------------------------------------------------------------
// evec[l][t][h] = (dot(elk[t], wr_w[l]) + wr_b[l]) * elk[t][h]
__global__ void k_evec(const float* __restrict__ elk, const float* __restrict__ wr_w,
                       const float* __restrict__ wr_b, float* __restrict__ evec) {
    int idx = blockIdx.x;
    int l = idx / ETYPES, t = idx % ETYPES;
    int h = threadIdx.x;
    float eh = elk[(size_t)t * DIM + h];
    float p = eh * wr_w[l * DIM + h];
    for (int off = 32; off; off >>= 1) p += __shfl_down(p, off, 64);
    __shared__ float ws2[2];
    if ((threadIdx.x & 63) == 0) ws2[threadIdx.x >> 6] = p;
    __syncthreads();
    float wr = ws2[0] + ws2[1] + wr_b[l];
    evec[((size_t)l * ETYPES + t) * DIM + h] = wr * eh;
}

// ---------------------------------------------------------------------------
// beta[l][b][j] = tanh(dot(visit_node[b,j], beta_w[l]) + beta_b[l]) * exp(DECAY*(MV-j))
__global__ void k_beta(const float* __restrict__ visit_node, const float* __restrict__ beta_w,
                       const float* __restrict__ beta_b, float* __restrict__ beta) {
    int idx = blockIdx.x;
    int l = idx >> 6, b = idx & 63;
    int wave = threadIdx.x >> 6, lane = threadIdx.x & 63;
    const float* bw = beta_w + (size_t)l * VOCAB;
    for (int j = wave; j < MV; j += 4) {
        const float* vn = visit_node + ((size_t)b * MV + j) * VOCAB;
        float acc = 0.f;
        for (int k = lane * 4; k < VOCAB; k += 256) {
            float4 a = *(const float4*)(vn + k);
            float4 w = *(const float4*)(bw + k);
            acc += a.x * w.x + a.y * w.y + a.z * w.z + a.w * w.w;
        }
        for (int off = 32; off; off >>= 1) acc += __shfl_down(acc, off, 64);
        if (lane == 0) {
            float lam = __expf(DECAYF * (float)(MV - j));
            beta[((size_t)l * NGRAPH + b) * MV + j] = tanhf(acc + beta_b[l]) * lam;
        }
    }
}

// ---------------------------------------------------------------------------
// gstart[b] = first index i with batch[i] >= b  (batch is sorted); gstart[NGRAPH] = N
__global__ void k_gbounds(const int* __restrict__ batch, int n_nodes, int* __restrict__ gstart) {
    int b = threadIdx.x;
    if (b > NGRAPH) return;
    int lo = 0, hi = n_nodes;
    while (lo < hi) { int mid = (lo + hi) >> 1; if (batch[mid] < b) lo = mid + 1; else hi = mid; }
    gstart[b] = lo;
}

// ---------------------------------------------------------------------------
// ---- CSR-by-dst build: histogram -> scan -> scatter (per-call, capture-safe)
__global__ void k_hist(const int* __restrict__ edst, int* __restrict__ cnt, int n_edges) {
    int e = blockIdx.x * 256 + threadIdx.x;
    if (e < n_edges) atomicAdd(&cnt[edst[e]], 1);
}

// per-block reduce of SCAN_B counts -> bsum[block]
__global__ void k_scan1(const int* __restrict__ cnt, int* __restrict__ bsum, int n_nodes) {
    __shared__ int s[256];
    int base = blockIdx.x * SCAN_B;
    int v = 0;
    int i0 = base + threadIdx.x;
    if (i0 < n_nodes) v += cnt[i0];
    if (i0 + 256 < n_nodes) v += cnt[i0 + 256];
    s[threadIdx.x] = v;
    __syncthreads();
    for (int st = 128; st > 0; st >>= 1) {
        if (threadIdx.x < st) s[threadIdx.x] += s[threadIdx.x + st];
        __syncthreads();
    }
    if (threadIdx.x == 0) bsum[blockIdx.x] = s[0];
}

// single-block inclusive scan of bsum (nb <= 256)
__global__ void k_scan2(int* __restrict__ bsum, int nb) {
    __shared__ int s[256];
    int t = threadIdx.x;
    s[t] = (t < nb) ? bsum[t] : 0;
    __syncthreads();
    for (int st = 1; st < 256; st <<= 1) {
        int u = (t >= st) ? s[t - st] : 0;
        __syncthreads();
        s[t] += u;
        __syncthreads();
    }
    if (t < nb) bsum[t] = s[t];   // inclusive
}

// per-block exclusive scan + base -> offsets, cursor; offsets[N] gets E
__global__ void k_scan3(const int* __restrict__ cnt, const int* __restrict__ bsum,
                        int* __restrict__ offsets, int* __restrict__ cursor, int n_nodes) {
    __shared__ int s[SCAN_B];
    int b = blockIdx.x;
    int base = b * SCAN_B;
    int t = threadIdx.x;                       // 512 threads
    int v = (base + t < n_nodes) ? cnt[base + t] : 0;
    s[t] = v;
    __syncthreads();
    for (int st = 1; st < SCAN_B; st <<= 1) {
        int u = (t >= st) ? s[t - st] : 0;
        __syncthreads();
        s[t] += u;
        __syncthreads();
    }
    int gbase = (b == 0) ? 0 : bsum[b - 1];
    int excl = gbase + s[t] - v;
    if (base + t <= n_nodes) {
        offsets[base + t] = excl;              // offsets[N] == E falls out naturally
        if (base + t < n_nodes) cursor[base + t] = excl;
    }
}

// Scatter per-edge records:
//   sorted_p[p] = src | (edge_type << 17)   (N = 50000 < 2^17, ETYPES = 500 < 2^15)
//   sorted_v[p] = node_ids[src]             (vocab id; lives in the x0 overlay,
//                                            consumed only by layer-0 aggconv)
__global__ void k_scatter(const int* __restrict__ edst, const int* __restrict__ esrc,
                          const int* __restrict__ edge_ids, const int* __restrict__ node_ids,
                          int* __restrict__ cursor, unsigned* __restrict__ sorted_p,
                          unsigned* __restrict__ sorted_v, int n_edges) {
    int e = blockIdx.x * 256 + threadIdx.x;
    if (e < n_edges) {
        int s = esrc[e];
        int p = atomicAdd(&cursor[edst[e]], 1);
        sorted_p[p] = (unsigned)s | ((unsigned)edge_ids[e] << 17);
        sorted_v[p] = (unsigned)node_ids[s];
    }
}

// ---------------------------------------------------------------------------
// Per-node attention: attnn[i] = sum_j softmax_j(visit_node[b]·alpha_w[v]) * beta[b][j]
__global__ __launch_bounds__(256, 2) void k_attn_node(
        const float* __restrict__ visit_node, const float* __restrict__ alpha_w_l,
        const float* __restrict__ beta_l, const int* __restrict__ node_ids,
        const int* __restrict__ gstart, float* __restrict__ attnn) {
    __shared__ float As[MV][KC + 4];
    int b = blockIdx.x;
    int start = gstart[b], end = gstart[b + 1];
    int wave = threadIdx.x >> 6, lane = threadIdx.x & 63;
    const float* bet = beta_l + (size_t)b * MV;

    for (int base = start + blockIdx.y * 16; base < end; base += gridDim.y * 16) {
        int n0 = base + wave * 4;
        int v[4]; bool valid[4];
#pragma unroll
        for (int i = 0; i < 4; i++) {
            int n = n0 + i;
            valid[i] = (n < end);
            v[i] = valid[i] ? node_ids[n] : 0;
        }
        float acc[4][MV];
#pragma unroll
        for (int i = 0; i < 4; i++)
#pragma unroll
            for (int j = 0; j < MV; j++) acc[i][j] = 0.f;

        for (int k0 = 0; k0 < VOCAB; k0 += KC) {
            __syncthreads();
            for (int idx = threadIdx.x; idx < MV * (KC / 4); idx += 256) {
                int j = idx / (KC / 4), kq = idx % (KC / 4);
                float4 vv = *(const float4*)(visit_node + ((size_t)b * MV + j) * VOCAB + k0 + kq * 4);
                *(float4*)&As[j][kq * 4] = vv;
            }
            __syncthreads();
#pragma unroll
            for (int step = 0; step < KC / 256; step++) {
                int kk = step * 256 + lane * 4;
                float4 a[4];
#pragma unroll
                for (int i = 0; i < 4; i++)
                    a[i] = *(const float4*)(alpha_w_l + (size_t)v[i] * VOCAB + k0 + kk);
#pragma unroll
                for (int j = 0; j < MV; j++) {
                    float4 s = *(const float4*)&As[j][kk];
#pragma unroll
                    for (int i = 0; i < 4; i++)
                        acc[i][j] += a[i].x * s.x + a[i].y * s.y + a[i].z * s.z + a[i].w * s.w;
                }
            }
        }
#pragma unroll
        for (int i = 0; i < 4; i++)
#pragma unroll
            for (int j = 0; j < MV; j++)
                for (int off = 32; off; off >>= 1)
                    acc[i][j] += __shfl_xor(acc[i][j], off, 64);

#pragma unroll
        for (int i = 0; i < 4; i++) {
            if (!valid[i]) continue;
            float m = -1e30f;
#pragma unroll
            for (int j = 0; j < MV; j++) m = fmaxf(m, acc[i][j]);
            float den = 0.f, num = 0.f;
#pragma unroll
            for (int j = 0; j < MV; j++) {
                float e = __expf(acc[i][j] - m);
                den += e;
                num += e * bet[j];
            }
            if (lane == 0) attnn[n0 + i] = num / den;
        }
    }
}

// ---------------------------------------------------------------------------
// Fused aggregate + GIN conv, CSR by dst (no atomics).
// Block = 256 thr = 4 waves; wave w aggregates node n0+w, lane handles dims
// 2*lane, 2*lane+1 (float2).  Edge loop unrolled by 4 with named scalars.
// NOTE: NO occupancy minimum in launch_bounds -- rounds 1/4 proved that a
// floor of 3-4 waves/EU forces the allocator to spill the unrolled live set
// to scratch (WRITE_SIZE 1.4-2.0 GB vs the legit 26 MB). Let VGPRs float
// (~150); ~3 waves/SIMD + 12 independent loads/quad is enough MLP.
// USE_TAB=1 (layer 0): x rows come from the 4096-row x0lk table (2 MB, L2-
// resident) indexed by the sorted_v vocab stream -- bit-identical to
// gathering the staged x0[src] row.
template<int USE_TAB>
__global__ __launch_bounds__(256) void k_aggconv(
        const float* __restrict__ xin, const float* __restrict__ xtab,
        const int* __restrict__ node_ids, float* __restrict__ xout,
        const float* __restrict__ attnn, const float* __restrict__ evec_l,
        const unsigned* __restrict__ sorted_p, const unsigned* __restrict__ sorted_v,
        const int* __restrict__ offsets,
        const float* __restrict__ conv_w_l, const float* __restrict__ conv_b_l,
        const float* __restrict__ eps, int l, int n_nodes) {
    int n0 = blockIdx.x * 4;
    int wave = threadIdx.x >> 6, lane = threadIdx.x & 63;
    int lane2 = lane * 2;
    int n = n0 + wave;
    __shared__ float t[4][DIM];
    float c = 1.0f + eps[l];

    if (n < n_nodes) {
        float accx = 0.f, accy = 0.f;
        int i0 = offsets[n], i1 = offsets[n + 1];
        int idx = i0;
        for (; idx + 4 <= i1; idx += 4) {
            unsigned p0 = sorted_p[idx];
            unsigned p1 = sorted_p[idx + 1];
            unsigned p2 = sorted_p[idx + 2];
            unsigned p3 = sorted_p[idx + 3];
            unsigned r0 = USE_TAB ? sorted_v[idx]     : (p0 & 0x1FFFFu);
            unsigned r1 = USE_TAB ? sorted_v[idx + 1] : (p1 & 0x1FFFFu);
            unsigned r2 = USE_TAB ? sorted_v[idx + 2] : (p2 & 0x1FFFFu);
            unsigned r3 = USE_TAB ? sorted_v[idx + 3] : (p3 & 0x1FFFFu);
            const float* xb = USE_TAB ? xtab : xin;
            float a0 = attnn[p0 & 0x1FFFFu];
            float a1 = attnn[p1 & 0x1FFFFu];
            float a2 = attnn[p2 & 0x1FFFFu];
            float a3 = attnn[p3 & 0x1FFFFu];
            float2 xv0 = *(const float2*)(xb + (size_t)r0 * DIM + lane2);
            float2 xv1 = *(const float2*)(xb + (size_t)r1 * DIM + lane2);
            float2 xv2 = *(const float2*)(xb + (size_t)r2 * DIM + lane2);
            float2 xv3 = *(const float2*)(xb + (size_t)r3 * DIM + lane2);
            float2 ev0 = *(const float2*)(evec_l + (size_t)(p0 >> 17) * DIM + lane2);
            float2 ev1 = *(const float2*)(evec_l + (size_t)(p1 >> 17) * DIM + lane2);
            float2 ev2 = *(const float2*)(evec_l + (size_t)(p2 >> 17) * DIM + lane2);
            float2 ev3 = *(const float2*)(evec_l + (size_t)(p3 >> 17) * DIM + lane2);
            accx += fmaxf(xv0.x * a0 + ev0.x, 0.f);
            accy += fmaxf(xv0.y * a0 + ev0.y, 0.f);
            accx += fmaxf(xv1.x * a1 + ev1.x, 0.f);
            accy += fmaxf(xv1.y * a1 + ev1.y, 0.f);
            accx += fmaxf(xv2.x * a2 + ev2.x, 0.f);
            accy += fmaxf(xv2.y * a2 + ev2.y, 0.f);
            accx += fmaxf(xv3.x * a3 + ev3.x, 0.f);
            accy += fmaxf(xv3.y * a3 + ev3.y, 0.f);
        }
        for (; idx < i1; idx++) {
            unsigned p = sorted_p[idx];
            unsigned r = USE_TAB ? sorted_v[idx] : (p & 0x1FFFFu);
            const float* xb = USE_TAB ? xtab : xin;
            float av = attnn[p & 0x1FFFFu];
            float2 xv = *(const float2*)(xb + (size_t)r * DIM + lane2);
            float2 ev = *(const float2*)(evec_l + (size_t)(p >> 17) * DIM + lane2);
            accx += fmaxf(xv.x * av + ev.x, 0.f);
            accy += fmaxf(xv.y * av + ev.y, 0.f);
        }
        const float* selfr = USE_TAB ? xtab + (size_t)node_ids[n] * DIM : xin + (size_t)n * DIM;
        float2 xn = *(const float2*)(selfr + lane2);
        t[wave][lane2]     = accx + c * xn.x;
        t[wave][lane2 + 1] = accy + c * xn.y;
    }
    __syncthreads();

    int h = threadIdx.x & 127;
    int g = threadIdx.x >> 7;                  // handles nodes g and g+2
    const float4* w4 = (const float4*)(conv_w_l + (size_t)h * DIM);
    float cb = conv_b_l[h];
    float acc0 = cb, acc1 = cb;
#pragma unroll
    for (int k = 0; k < DIM / 4; k++) {
        float4 w = w4[k];
        float4 u0 = *(const float4*)&t[g][k * 4];
        float4 u1 = *(const float4*)&t[g + 2][k * 4];
        acc0 += w.x * u0.x + w.y * u0.y + w.z * u0.z + w.w * u0.w;
        acc1 += w.x * u1.x + w.y * u1.y + w.z * u1.z + w.w * u1.w;
    }
    if (n0 + g < n_nodes)     xout[(size_t)(n0 + g) * DIM + h]     = fmaxf(acc0, 0.f);
    if (n0 + g + 2 < n_nodes) xout[(size_t)(n0 + g + 2) * DIM + h] = fmaxf(acc1, 0.f);
}

// ---------------------------------------------------------------------------
// gsum[b][h] = mean over nodes of graph b of x[i][h]
__global__ void k_pool(const float* __restrict__ x, const int* __restrict__ gstart,
                       float* __restrict__ gsum) {
    int b = blockIdx.x;
    int start = gstart[b], end = gstart[b + 1];
    int half = threadIdx.x >> 7, h = threadIdx.x & 127;
    float acc = 0.f;
    for (int i = start + half; i < end; i += 2) acc += x[(size_t)i * DIM + h];
    __shared__ float sm[2][DIM];
    sm[half][h] = acc;
    __syncthreads();
    if (half == 0) {
        int cnt = end - start;
        gsum[(size_t)b * DIM + h] = (sm[0][h] + sm[1][h]) / (float)(cnt > 1 ? cnt : 1);
    }
}

// ---------------------------------------------------------------------------
// xnode[b][d] = (sum_v ehr[b][v]*node_emb[v][d]) / sum_v ehr[b][v]
__global__ void k_xnode(const float* __restrict__ ehr, const float* __restrict__ node_emb,
                        float* __restrict__ xnode) {
    int b = blockIdx.x, d = threadIdx.x;
    const float* e = ehr + (size_t)b * VOCAB;
    float acc = 0.f;
    for (int v = 0; v < VOCAB; v++) acc += e[v] * node_emb[(size_t)v * DIM + d];
    float ps = 0.f;
    for (int v = d; v < VOCAB; v += DIM) ps += e[v];
    __shared__ float red[DIM];
    red[d] = ps;
    __syncthreads();
    for (int s = DIM / 2; s > 0; s >>= 1) {
        if (d < s) red[d] += red[d + s];
        __syncthreads();
    }
    xnode[(size_t)b * DIM + d] = acc / red[0];
}

// ---------------------------------------------------------------------------
__global__ void k_head(const float* __restrict__ gsum, const float* __restrict__ xnode2,
                       const float* __restrict__ mlp_w, const float* __restrict__ mlp_b,
                       float* __restrict__ out) {
    int b = blockIdx.x, o = threadIdx.x;
    if (o >= OUTC) return;
    const float* w = mlp_w + (size_t)o * 2 * DIM;
    float acc = mlp_b[o];
    for (int h = 0; h < DIM; h++)
        acc += gsum[(size_t)b * DIM + h] * w[h] + xnode2[(size_t)b * DIM + h] * w[DIM + h];
    out[(size_t)b * OUTC + o] = acc;
}

// ---------------------------------------------------------------------------
extern "C" void kernel_launch(void* const* d_in, const int* in_sizes, int n_in,
                              void* d_out, int out_size, void* d_ws, size_t ws_size,
                              hipStream_t stream) {
    const int*   node_ids   = (const int*)d_in[0];
    const int*   edge_ids   = (const int*)d_in[1];
    const int*   edge_index = (const int*)d_in[2];
    const float* visit_node = (const float*)d_in[6];
    const float* ehr        = (const float*)d_in[7];
    const int*   batch      = (const int*)d_in[8];
    const float* node_emb   = (const float*)d_in[10];
    const float* edge_emb   = (const float*)d_in[11];
    const float* lin_w      = (const float*)d_in[12];
    const float* lin_b      = (const float*)d_in[13];
    const float* alpha_w    = (const float*)d_in[14];
    // d_in[15] alpha_b: cancels in softmax over visits — unused
    const float* beta_w     = (const float*)d_in[16];
    const float* beta_b     = (const float*)d_in[17];
    const float* conv_w     = (const float*)d_in[18];
    const float* conv_b     = (const float*)d_in[19];
    const float* wr_w       = (const float*)d_in[20];
    const float* wr_b       = (const float*)d_in[21];
    const float* eps        = (const float*)d_in[22];
    const float* mlp_w      = (const float*)d_in[23];
    const float* mlp_b      = (const float*)d_in[24];
    float* out = (float*)d_out;

    const int N = in_sizes[0];
    const int E = in_sizes[1];
    const int NB = (N + SCAN_B - 1) / SCAN_B;       // scan blocks (<=256)

    // ---- workspace layout (floats) — BYTE-IDENTICAL to the proven round-1
    // layout (58.2 MB). sorted_v is an overlay inside x0: x0 is only written
    // by the layer-1 aggconv, strictly after sorted_v's last read (layer-0
    // aggconv) on the same stream.
    float* w = (float*)d_ws;
    size_t off = 0;
    float* x0     = w + off; off += (size_t)N * DIM;
    float* x1     = w + off; off += (size_t)N * DIM;
    float* attnn  = w + off; off += ((size_t)N + 3) & ~(size_t)3;
    float* beta   = w + off; off += (size_t)NLAYERS * NGRAPH * MV;
    float* x0lk   = w + off; off += (size_t)VOCAB * DIM;
    float* elk    = w + off; off += (size_t)ETYPES * DIM;
    float* evec   = w + off; off += (size_t)NLAYERS * ETYPES * DIM;
    float* gsum   = w + off; off += (size_t)NGRAPH * DIM;
    float* xnode  = w + off; off += (size_t)NGRAPH * DIM;
    float* xnode2 = w + off; off += (size_t)NGRAPH * DIM;
    int*   gstart = (int*)(w + off); off += NGRAPH + 8;
    int*   cnt      = (int*)(w + off); off += (size_t)N + 8;
    int*   offsets  = (int*)(w + off); off += (size_t)N + 8;
    int*   cursor   = (int*)(w + off); off += (size_t)N + 8;
    int*   bsum     = (int*)(w + off); off += 256 + 8;
    unsigned* sorted_p = (unsigned*)(w + off); off += (size_t)E;
    unsigned* sorted_v = (unsigned*)x0;             // overlay (E <= N*DIM)

    const int* esrc = edge_index;
    const int* edst = edge_index + E;

    // ---- CSR-by-dst build ----
    hipMemsetAsync(cnt, 0, (size_t)N * sizeof(int), stream);
    k_hist<<<(E + 255) / 256, 256, 0, stream>>>(edst, cnt, E);
    k_scan1<<<NB, 256, 0, stream>>>(cnt, bsum, N);
    k_scan2<<<1, 256, 0, stream>>>(bsum, NB);
    k_scan3<<<NB, SCAN_B, 0, stream>>>(cnt, bsum, offsets, cursor, N);
    k_scatter<<<(E + 255) / 256, 256, 0, stream>>>(edst, esrc, edge_ids, node_ids,
                                                   cursor, sorted_p, sorted_v, E);

    // ---- precompute tables ----
    k_rowlin<<<VOCAB, DIM, 0, stream>>>(node_emb, x0lk, lin_w, lin_b);
    k_rowlin<<<ETYPES, DIM, 0, stream>>>(edge_emb, elk, lin_w, lin_b);
    k_evec<<<NLAYERS * ETYPES, DIM, 0, stream>>>(elk, wr_w, wr_b, evec);
    k_beta<<<NLAYERS * NGRAPH, 256, 0, stream>>>(visit_node, beta_w, beta_b, beta);
    k_gbounds<<<1, 128, 0, stream>>>(batch, N, gstart);

    // ---- layer 0: x rows come straight from the x0lk vocab table ----
    k_attn_node<<<dim3(NGRAPH, 40), 256, 0, stream>>>(
        visit_node, alpha_w, beta, node_ids, gstart, attnn);
    k_aggconv<1><<<(N + 3) / 4, 256, 0, stream>>>(
        x0lk, x0lk, node_ids, x1, attnn, evec,
        sorted_p, sorted_v, offsets, conv_w, conv_b, eps, 0, N);

    // ---- layer 1: x rows gathered from x1 ----
    k_attn_node<<<dim3(NGRAPH, 40), 256, 0, stream>>>(
        visit_node, alpha_w + (size_t)VOCAB * VOCAB,
        beta + (size_t)NGRAPH * MV, node_ids, gstart, attnn);
    k_aggconv<0><<<(N + 3) / 4, 256, 0, stream>>>(
        x1, x0lk, node_ids, x0, attnn, evec + (size_t)ETYPES * DIM,
        sorted_p, sorted_v, offsets, conv_w + (size_t)DIM * DIM, conv_b + DIM, eps, 1, N);

    // ---- heads ----
    k_pool<<<NGRAPH, 256, 0, stream>>>(x0, gstart, gsum);
    k_xnode<<<NGRAPH, DIM, 0, stream>>>(ehr, node_emb, xnode);
    k_rowlin<<<NGRAPH, DIM, 0, stream>>>(xnode, xnode2, lin_w, lin_b);
    k_head<<<NGRAPH, 64, 0, stream>>>(gsum, xnode2, mlp_w, mlp_b, out);
}